// Round 14
// baseline (169.709 us; speedup 1.0000x reference)
//
#include <hip/hip_runtime.h>

typedef __bf16 bf16_t;
typedef bf16_t bf16x8 __attribute__((ext_vector_type(8)));
typedef bf16_t bf16x4 __attribute__((ext_vector_type(4)));
typedef float  f32x4  __attribute__((ext_vector_type(4)));
typedef float  f32x16 __attribute__((ext_vector_type(16)));
typedef unsigned int u32;
typedef u32 u32x2 __attribute__((ext_vector_type(2)));
typedef u32 u32x4 __attribute__((ext_vector_type(4)));

#define T_SEQ 2048
#define C_DIM 1024
#define NH    16
#define DH    64
#define BATCH 4
#define M_TOK (BATCH * T_SEQ)   // 8192

// Q pre-scale: 1/sqrt(64) * log2(e)  -> softmax computed in exp2 domain
#define Q_SCALE 0.1803368801111137f
#define DEFER_THR 8.0f

#define AS1 __attribute__((address_space(1)))
#define AS3 __attribute__((address_space(3)))

__device__ __forceinline__ void gld_lds16(const bf16_t* g, bf16_t* l) {
  __builtin_amdgcn_global_load_lds(
      (const AS1 u32*)(uintptr_t)g,
      (AS3 u32*)(u32)(uintptr_t)l, 16, 0, 0);
}

// v_permlane32_swap_b32: swaps a[32+i] <-> b[i].
__device__ __forceinline__ void plswap(u32& a, u32& b) {
  u32x2 r = __builtin_amdgcn_permlane32_swap(a, b, false, false);
  a = r[0]; b = r[1];
}
__device__ __forceinline__ float xmax32(float x) {
  u32 a = __builtin_bit_cast(u32, x), b = a;
  plswap(a, b);
  return fmaxf(__builtin_bit_cast(float, a), __builtin_bit_cast(float, b));
}
__device__ __forceinline__ float xsum32(float x) {
  u32 a = __builtin_bit_cast(u32, x), b = a;
  plswap(a, b);
  return __builtin_bit_cast(float, a) + __builtin_bit_cast(float, b);
}

__device__ __forceinline__ u32 pack_bf16_pair(float v0, float v1) {
  const unsigned short b0 = __builtin_bit_cast(unsigned short, (bf16_t)v0);
  const unsigned short b1 = __builtin_bit_cast(unsigned short, (bf16_t)v1);
  return ((u32)b1 << 16) | (u32)b0;
}

// ---------------------------------------------------------------------------
// prep: x f32 -> bf16
// ---------------------------------------------------------------------------
__global__ __launch_bounds__(256) void msa_cvt_x(const float* __restrict__ x,
                                                 bf16_t* __restrict__ xb, int n4) {
  int i = blockIdx.x * 256 + threadIdx.x;
  if (i < n4) {
    const float4 v = ((const float4*)x)[i];
    bf16x4 o;
    o[0] = (bf16_t)v.x; o[1] = (bf16_t)v.y; o[2] = (bf16_t)v.z; o[3] = (bf16_t)v.w;
    ((bf16x4*)xb)[i] = o;
  }
}

// ---------------------------------------------------------------------------
// prep: weight transpose+convert: w[k][n] f32 -> wt[n][k] bf16
// ---------------------------------------------------------------------------
__global__ __launch_bounds__(256) void msa_transpose_w(
    const float* __restrict__ wq, const float* __restrict__ wk,
    const float* __restrict__ wv, const float* __restrict__ wo,
    bf16_t* __restrict__ wt_qkv, bf16_t* __restrict__ wt_o) {
  __shared__ float tile[32][33];
  const int a = blockIdx.z;
  const float* src = (a == 0) ? wq : (a == 1) ? wk : (a == 2) ? wv : wo;
  bf16_t* dst = (a < 3) ? (wt_qkv + (size_t)a * C_DIM * C_DIM) : wt_o;
  const int tx = threadIdx.x & 31, ty = threadIdx.x >> 5;
  const int bi = blockIdx.y * 32, bj = blockIdx.x * 32;
#pragma unroll
  for (int p = 0; p < 4; p++) {
    int r = p * 8 + ty;
    tile[r][tx] = src[(size_t)(bi + r) * C_DIM + bj + tx];
  }
  __syncthreads();
#pragma unroll
  for (int p = 0; p < 4; p++) {
    int r = p * 8 + ty;
    dst[(size_t)(bj + r) * C_DIM + bi + tx] = (bf16_t)tile[tx][r];
  }
}

// ---------------------------------------------------------------------------
// GEMM core (R12-verified), R14: XCD remap REVERTED (default interleave has
// 768KB per-XCD B-footprint; the chunked remap replicated a 6MB B panel per
// XCD -> FETCH 80->124MB measured).  128x128 tile, BK=32, 3-deep LDS
// rotation (48KB), counted vmcnt(4) in-loop with vmcnt(0) on the final two
// iterations, setprio around the MFMA cluster.
// ---------------------------------------------------------------------------
#define GQ_BUF 16384

#define GEMM_CORE(APTR, BPTR, NT)                                              \
  __shared__ __align__(16) char lds[3 * GQ_BUF];                               \
  const int tid = threadIdx.x;                                                 \
  const int w = tid >> 6, lane = tid & 63;                                     \
  const int lr = lane & 15, lg = lane >> 4;                                    \
  const int m0 = blockIdx.y * 128;                                             \
  const int n0 = blockIdx.x * 128;                                             \
  const int wm = (w >> 1) * 64, wn = (w & 1) * 64;                             \
  const int rsw = (lg * 16) ^ ((lr & 3) << 4);                                 \
  int Aoff[4], Boff[4];                                                        \
  _Pragma("unroll") for (int f = 0; f < 4; f++) {                              \
    Aoff[f] = (wm + f * 16 + lr) * 64 + rsw;                                   \
    Boff[f] = 8192 + (wn + f * 16 + lr) * 64 + rsw;                            \
  }                                                                            \
  const int idx0 = tid, idx1 = 256 + tid;                                      \
  const int r0 = idx0 >> 2, c0_ = ((idx0 & 3) ^ (r0 & 3)) * 8;                 \
  const int r1 = idx1 >> 2, c1_ = ((idx1 & 3) ^ (r1 & 3)) * 8;                 \
  const bf16_t* gA0 = (APTR) + (size_t)(m0 + r0) * C_DIM + c0_;                \
  const bf16_t* gA1 = (APTR) + (size_t)(m0 + r1) * C_DIM + c1_;                \
  const bf16_t* gB0 = (BPTR) + (size_t)(n0 + r0) * C_DIM + c0_;                \
  const bf16_t* gB1 = (BPTR) + (size_t)(n0 + r1) * C_DIM + c1_;                \
  f32x4 acc[4][4];                                                             \
  _Pragma("unroll") for (int i = 0; i < 4; i++)                                \
    _Pragma("unroll") for (int j = 0; j < 4; j++)                              \
      acc[i][j] = (f32x4){0.f, 0.f, 0.f, 0.f};                                 \
  GSTG(0, 0);                                                                  \
  GSTG(1, GQ_BUF);                                                             \
  asm volatile("s_waitcnt vmcnt(4)" ::: "memory");                             \
  __builtin_amdgcn_s_barrier();                                                \
  __builtin_amdgcn_sched_barrier(0);                                           \
  int cb = 0;                                                                  \
  for (int kt = 0; kt < (NT); ++kt) {                                          \
    const char* base = lds + cb * GQ_BUF;                                      \
    bf16x8 a[4], b[4];                                                         \
    _Pragma("unroll") for (int f = 0; f < 4; f++) {                            \
      a[f] = *(const bf16x8*)(base + Aoff[f]);                                 \
      b[f] = *(const bf16x8*)(base + Boff[f]);                                 \
    }                                                                          \
    if (kt < (NT)-2) {                                                         \
      int sb = cb + 2; if (sb >= 3) sb -= 3;                                   \
      GSTG(kt + 2, sb * GQ_BUF);                                               \
    }                                                                          \
    __builtin_amdgcn_s_setprio(1);                                             \
    _Pragma("unroll") for (int mf = 0; mf < 4; mf++)                           \
      _Pragma("unroll") for (int nf = 0; nf < 4; nf++)                         \
        acc[mf][nf] = __builtin_amdgcn_mfma_f32_16x16x32_bf16(                 \
            a[mf], b[nf], acc[mf][nf], 0, 0, 0);                               \
    __builtin_amdgcn_s_setprio(0);                                             \
    if (kt < (NT)-2) {                                                         \
      asm volatile("s_waitcnt vmcnt(4)" ::: "memory");                         \
    } else {                                                                   \
      asm volatile("s_waitcnt vmcnt(0)" ::: "memory");                         \
    }                                                                          \
    __builtin_amdgcn_s_barrier();                                              \
    __builtin_amdgcn_sched_barrier(0);                                         \
    if (++cb == 3) cb = 0;                                                     \
  }

#define GSTG(KT, BB)                                                           \
  {                                                                            \
    bf16_t* d_ = (bf16_t*)(lds + (BB));                                        \
    gld_lds16(gA0 + (KT) * 32, d_ + tid * 8);                                  \
    gld_lds16(gA1 + (KT) * 32, d_ + 2048 + tid * 8);                           \
    gld_lds16(gB0 + (KT) * 32, d_ + 4096 + tid * 8);                           \
    gld_lds16(gB1 + (KT) * 32, d_ + 6144 + tid * 8);                           \
  }

// ---------------------------------------------------------------------------
// QKV GEMM -> Q (scaled), K, Vt.  V-blocks use packed 8B scatter.
// ---------------------------------------------------------------------------
__global__ __launch_bounds__(256, 3) void msa_gemm_qkv(
    const bf16_t* __restrict__ xb, const bf16_t* __restrict__ wt,
    const float* __restrict__ bq, const float* __restrict__ bk,
    const float* __restrict__ bv,
    bf16_t* __restrict__ qo, bf16_t* __restrict__ ko, bf16_t* __restrict__ vto) {
  GEMM_CORE(xb, wt, 32)

  const int g = n0 >> 10;  // uniform per block
  if (g == 2) {
#pragma unroll
    for (int nb = 0; nb < 4; nb++) {
      const int c = ((n0 + wn) & 1023) + nb * 16 + lr;
      const int h = c >> 6, d = c & 63;
      const float bias = bv[c];
      bf16_t* vrow = vto + (((size_t)((m0 >> 11) * NH + h)) * DH + d) * T_SEQ;
#pragma unroll
      for (int mb = 0; mb < 4; mb++) {
        const int t = (m0 & 2047) + wm + mb * 16 + lg * 4;
        u32x2 pr;
        pr[0] = pack_bf16_pair(acc[mb][nb][0] + bias, acc[mb][nb][1] + bias);
        pr[1] = pack_bf16_pair(acc[mb][nb][2] + bias, acc[mb][nb][3] + bias);
        *reinterpret_cast<u32x2*>(vrow + t) = pr;
      }
    }
  } else {
#pragma unroll
    for (int nb = 0; nb < 4; nb++) {
      const int n = n0 + wn + nb * 16 + lr;
      const int c = n & 1023, h = c >> 6, d = c & 63;
      const float bias = (g == 0) ? bq[c] : bk[c];
#pragma unroll
      for (int mb = 0; mb < 4; mb++) {
#pragma unroll
        for (int r = 0; r < 4; r++) {
          const int m = m0 + wm + mb * 16 + lg * 4 + r;
          const int bi = m >> 11, t = m & (T_SEQ - 1);
          float v = acc[mb][nb][r] + bias;
          if (g == 0)
            qo[(((size_t)bi * NH + h) * T_SEQ + t) * DH + d] = (bf16_t)(v * Q_SCALE);
          else
            ko[(((size_t)bi * NH + h) * T_SEQ + t) * DH + d] = (bf16_t)v;
        }
      }
    }
  }
}

// ---------------------------------------------------------------------------
// Output projection
// ---------------------------------------------------------------------------
__global__ __launch_bounds__(256, 3) void msa_gemm_out(
    const bf16_t* __restrict__ ab, const bf16_t* __restrict__ wt,
    const float* __restrict__ bo, float* __restrict__ out) {
  GEMM_CORE(ab, wt, 32)

#pragma unroll
  for (int nb = 0; nb < 4; nb++) {
    const int n = n0 + wn + nb * 16 + lr;
    const float bias = bo[n];
#pragma unroll
    for (int mb = 0; mb < 4; mb++) {
#pragma unroll
      for (int r = 0; r < 4; r++) {
        const int m = m0 + wm + mb * 16 + lg * 4 + r;
        out[(size_t)m * C_DIM + n] = acc[mb][nb][r] + bias;
      }
    }
  }
}

// ---------------------------------------------------------------------------
// attn: softmax + pack helpers (permlane, no LDS)
// ---------------------------------------------------------------------------
__device__ __forceinline__ void pack_frag(const f32x16& s, bf16x8& pa0, bf16x8& pa1) {
  u32 pk8[8];
#pragma unroll
  for (int i = 0; i < 8; i++) pk8[i] = pack_bf16_pair(s[2 * i], s[2 * i + 1]);
  u32 f0w0 = pk8[0], f0w2 = pk8[2];
  u32 f0w1 = pk8[1], f0w3 = pk8[3];
  u32 f1w0 = pk8[4], f1w2 = pk8[6];
  u32 f1w1 = pk8[5], f1w3 = pk8[7];
  plswap(f0w0, f0w2);
  plswap(f0w1, f0w3);
  plswap(f1w0, f1w2);
  plswap(f1w1, f1w3);
  const u32x4 q0v = {f0w0, f0w1, f0w2, f0w3};
  const u32x4 q1v = {f1w0, f1w1, f1w2, f1w3};
  pa0 = __builtin_bit_cast(bf16x8, q0v);
  pa1 = __builtin_bit_cast(bf16x8, q1v);
}

__device__ __forceinline__ void sm_pack(f32x16& s, float& m_run, float& l_run,
                                        f32x16& o0, f32x16& o1,
                                        bf16x8& pa0, bf16x8& pa1) {
  float t0 = fmaxf(fmaxf(s[0], s[1]), s[2]);
  float t1 = fmaxf(fmaxf(s[3], s[4]), s[5]);
  float t2 = fmaxf(fmaxf(s[6], s[7]), s[8]);
  float t3 = fmaxf(fmaxf(s[9], s[10]), s[11]);
  float t4 = fmaxf(fmaxf(s[12], s[13]), s[14]);
  float t5 = fmaxf(fmaxf(t0, t1), s[15]);
  float mt = fmaxf(fmaxf(fmaxf(t2, t3), t4), t5);
  mt = xmax32(mt);

  if (__any(mt > m_run + DEFER_THR)) {
    const float mnew = fmaxf(m_run, mt);
    const float al = __builtin_amdgcn_exp2f(m_run - mnew);
    m_run = mnew;
    l_run *= al;
#pragma unroll
    for (int r = 0; r < 16; r++) { o0[r] *= al; o1[r] *= al; }
  }

#pragma unroll
  for (int r = 0; r < 16; r++) s[r] = __builtin_amdgcn_exp2f(s[r] - m_run);
  {
    float a0 = (s[0] + s[1]) + (s[2] + s[3]);
    float a1 = (s[4] + s[5]) + (s[6] + s[7]);
    float a2 = (s[8] + s[9]) + (s[10] + s[11]);
    float a3 = (s[12] + s[13]) + (s[14] + s[15]);
    l_run += xsum32((a0 + a1) + (a2 + a3));
  }
  pack_frag(s, pa0, pa1);
}

__device__ __forceinline__ void store_o(f32x16& o0, f32x16& o1, float l_fin,
                                        bf16_t* __restrict__ orow, const int hi) {
  const float inv = 1.0f / l_fin;
#pragma unroll
  for (int db = 0; db < 2; db++) {
#pragma unroll
    for (int r = 0; r < 16; r += 2) {
      const int d = db * 32 + (r & 3) + 8 * (r >> 2) + 4 * hi;
      const float v0 = (db ? o1[r] : o0[r]) * inv;
      const float v1 = (db ? o1[r + 1] : o0[r + 1]) * inv;
      *reinterpret_cast<u32*>(orow + d) = pack_bf16_pair(v0, v1);
    }
  }
}

// ---------------------------------------------------------------------------
// Flash attention (causal): LDS-staged K/V shared across 4 waves.
// R14: counted-vmcnt 3-buffer rotation (the R10 version drained the
// just-issued STAGE at every __syncthreads -> staging latency exposed per
// slot).  Now: issue STAGE(kt+2) at iteration top; end with vmcnt(2) while
// staging is live (retires STAGE(kt+1), leaves kt+2 in flight across the
// raw barrier) and vmcnt(0) on the last two slots.  KT_MAX >= 35 always.
// ---------------------------------------------------------------------------
__global__ __launch_bounds__(256, 2) void msa_attn_lds(
    const bf16_t* __restrict__ Q, const bf16_t* __restrict__ K,
    const bf16_t* __restrict__ Vt, bf16_t* __restrict__ O) {
  __shared__ __align__(16) char lds[3 * 8192];  // 3 x [K 4KB | V 4KB]
  const int tid = threadIdx.x;
  const int w = tid >> 6;
  const int lane = tid & 63;
  const int l31 = lane & 31;
  const int hi = lane >> 5;
  const int bh = blockIdx.x;
  const int pg = blockIdx.y;          // pg=0 (longest) dispatched first
  const int p = pg * 4 + w;
  const int tS = p, tL = 63 - p;
  const int q0S = tS * 32, q0L = tL * 32;
  const int KT_MAX = 63 - 4 * pg;

  const bf16_t* Qh = Q + (size_t)bh * T_SEQ * DH;
  const bf16_t* Kh = K + (size_t)bh * T_SEQ * DH;
  const bf16_t* Vh = Vt + (size_t)bh * DH * T_SEQ;

  bf16x8 qfL[4], qfS[4];
#pragma unroll
  for (int dc = 0; dc < 4; dc++) {
    qfL[dc] = *(const bf16x8*)(Qh + (size_t)(q0L + l31) * DH + dc * 16 + hi * 8);
    qfS[dc] = *(const bf16x8*)(Qh + (size_t)(q0S + l31) * DH + dc * 16 + hi * 8);
  }

  f32x16 oL0, oL1, oS0, oS1;
#pragma unroll
  for (int r = 0; r < 16; r++) { oL0[r] = 0.f; oL1[r] = 0.f; oS0[r] = 0.f; oS1[r] = 0.f; }
  float mL = -1e30f, lL = 0.f, mS = -1e30f, lS = 0.f;
  const f32x16 z16 = {};

  const int ksw = (l31 & 7) << 4;
  const int vsw = (l31 & 3) << 4;
  const int krow = tid >> 3;
  const int kce = ((16 * (tid & 7)) ^ ((krow & 7) << 4)) >> 1;
  const int vrow = tid >> 2;
  const int vce = ((16 * (tid & 3)) ^ ((vrow & 3) << 4)) >> 1;

#define STAGE(KT, BUF)                                                         \
  {                                                                            \
    const int jj = (KT) * 32;                                                  \
    bf16_t* base_ = (bf16_t*)(lds + (BUF) * 8192);                             \
    gld_lds16(Kh + (size_t)(jj + krow) * DH + kce, base_ + tid * 8);           \
    gld_lds16(Vh + (size_t)vrow * T_SEQ + jj + vce, base_ + 2048 + tid * 8);   \
  }

  STAGE(0, 0);
  STAGE(1, 1);
  asm volatile("s_waitcnt vmcnt(2)" ::: "memory");
  __builtin_amdgcn_s_barrier();
  __builtin_amdgcn_sched_barrier(0);

  int cb = 0;
  for (int kt = 0; kt <= KT_MAX; ++kt) {
    if (kt + 2 <= KT_MAX) {
      int sb = cb + 2; if (sb >= 3) sb -= 3;
      STAGE(kt + 2, sb);
    }

    const bool doL = (kt <= tL);
    if (doL) {
      const char* kb = lds + cb * 8192;
      const char* vb = kb + 4096;
      bf16x8 kf[4];
#pragma unroll
      for (int dc = 0; dc < 4; dc++)
        kf[dc] = *(const bf16x8*)(kb + l31 * 128 + ((dc * 32 + hi * 16) ^ ksw));
      const bf16x8 vf00 = *(const bf16x8*)(vb + l31 * 64 + ((hi * 16) ^ vsw));
      const bf16x8 vf01 = *(const bf16x8*)(vb + l31 * 64 + ((32 + hi * 16) ^ vsw));
      const bf16x8 vf10 = *(const bf16x8*)(vb + (32 + l31) * 64 + ((hi * 16) ^ vsw));
      const bf16x8 vf11 = *(const bf16x8*)(vb + (32 + l31) * 64 + ((32 + hi * 16) ^ vsw));

      const bool doS = (kt <= tS);
      f32x16 sL = __builtin_amdgcn_mfma_f32_32x32x16_bf16(kf[0], qfL[0], z16, 0, 0, 0);
#pragma unroll
      for (int dc = 1; dc < 4; dc++)
        sL = __builtin_amdgcn_mfma_f32_32x32x16_bf16(kf[dc], qfL[dc], sL, 0, 0, 0);
      f32x16 sS;
      if (doS) {
        sS = __builtin_amdgcn_mfma_f32_32x32x16_bf16(kf[0], qfS[0], z16, 0, 0, 0);
#pragma unroll
        for (int dc = 1; dc < 4; dc++)
          sS = __builtin_amdgcn_mfma_f32_32x32x16_bf16(kf[dc], qfS[dc], sS, 0, 0, 0);
      }
      if (kt == tL) {
#pragma unroll
        for (int r = 0; r < 16; r++) {
          const int jrow = (r & 3) + 8 * (r >> 2) + 4 * hi;
          if (jrow > l31) sL[r] = -1e30f;
        }
      }
      if (kt == tS) {
#pragma unroll
        for (int r = 0; r < 16; r++) {
          const int jrow = (r & 3) + 8 * (r >> 2) + 4 * hi;
          if (jrow > l31) sS[r] = -1e30f;
        }
      }
      bf16x8 paL0, paL1;
      sm_pack(sL, mL, lL, oL0, oL1, paL0, paL1);
      oL0 = __builtin_amdgcn_mfma_f32_32x32x16_bf16(vf00, paL0, oL0, 0, 0, 0);
      oL1 = __builtin_amdgcn_mfma_f32_32x32x16_bf16(vf10, paL0, oL1, 0, 0, 0);
      oL0 = __builtin_amdgcn_mfma_f32_32x32x16_bf16(vf01, paL1, oL0, 0, 0, 0);
      oL1 = __builtin_amdgcn_mfma_f32_32x32x16_bf16(vf11, paL1, oL1, 0, 0, 0);
      if (doS) {
        bf16x8 paS0, paS1;
        sm_pack(sS, mS, lS, oS0, oS1, paS0, paS1);
        oS0 = __builtin_amdgcn_mfma_f32_32x32x16_bf16(vf00, paS0, oS0, 0, 0, 0);
        oS1 = __builtin_amdgcn_mfma_f32_32x32x16_bf16(vf10, paS0, oS1, 0, 0, 0);
        oS0 = __builtin_amdgcn_mfma_f32_32x32x16_bf16(vf01, paS1, oS0, 0, 0, 0);
        oS1 = __builtin_amdgcn_mfma_f32_32x32x16_bf16(vf11, paS1, oS1, 0, 0, 0);
      }
    }

    if (kt < KT_MAX - 1) {
      asm volatile("s_waitcnt vmcnt(2)" ::: "memory");
    } else {
      asm volatile("s_waitcnt vmcnt(0)" ::: "memory");
    }
    __builtin_amdgcn_s_barrier();
    __builtin_amdgcn_sched_barrier(0);
    if (++cb == 3) cb = 0;
  }
#undef STAGE

  const int b = bh >> 4, h = bh & 15;
  store_o(oL0, oL1, lL, O + ((size_t)b * T_SEQ + q0L + l31) * C_DIM + h * DH, hi);
  store_o(oS0, oS1, lS, O + ((size_t)b * T_SEQ + q0S + l31) * C_DIM + h * DH, hi);
}

// ---------------------------------------------------------------------------
// launch
// ---------------------------------------------------------------------------
extern "C" void kernel_launch(void* const* d_in, const int* in_sizes, int n_in,
                              void* d_out, int out_size, void* d_ws, size_t ws_size,
                              hipStream_t stream) {
  const float* x  = (const float*)d_in[0];
  const float* wq = (const float*)d_in[2];
  const float* bq = (const float*)d_in[3];
  const float* wk = (const float*)d_in[4];
  const float* bk = (const float*)d_in[5];
  const float* wv = (const float*)d_in[6];
  const float* bv = (const float*)d_in[7];
  const float* wo = (const float*)d_in[8];
  const float* bo = (const float*)d_in[9];

  char* ws = (char*)d_ws;
  bf16_t* xb     = (bf16_t*)(ws);
  bf16_t* wt_qkv = (bf16_t*)(ws + (16ull << 20));
  bf16_t* wt_o   = (bf16_t*)(ws + (22ull << 20));
  bf16_t* qb     = (bf16_t*)(ws + (24ull << 20));
  bf16_t* kb     = (bf16_t*)(ws + (40ull << 20));
  bf16_t* vtb    = (bf16_t*)(ws + (56ull << 20));
  bf16_t* attn_o = xb;  // alias: xb dead after QKV GEMM

  const int n4 = M_TOK * C_DIM / 4;
  msa_cvt_x<<<n4 / 256, 256, 0, stream>>>(x, xb, n4);
  msa_transpose_w<<<dim3(32, 32, 4), 256, 0, stream>>>(wq, wk, wv, wo, wt_qkv, wt_o);
  msa_gemm_qkv<<<dim3(24, 64), 256, 0, stream>>>(xb, wt_qkv, bq, bk, bv, qb, kb, vtb);
  msa_attn_lds<<<dim3(64, 8), 256, 0, stream>>>(qb, kb, vtb, attn_o);
  msa_gemm_out<<<dim3(8, 64), 256, 0, stream>>>(attn_o, wt_o, bo, (float*)d_out);
}

// Round 15
// 162.139 us; speedup vs baseline: 1.0467x; 1.0467x over previous
//
#include <hip/hip_runtime.h>

typedef __bf16 bf16_t;
typedef bf16_t bf16x8 __attribute__((ext_vector_type(8)));
typedef bf16_t bf16x4 __attribute__((ext_vector_type(4)));
typedef float  f32x4  __attribute__((ext_vector_type(4)));
typedef float  f32x16 __attribute__((ext_vector_type(16)));
typedef unsigned int u32;
typedef u32 u32x2 __attribute__((ext_vector_type(2)));
typedef u32 u32x4 __attribute__((ext_vector_type(4)));

#define T_SEQ 2048
#define C_DIM 1024
#define NH    16
#define DH    64
#define BATCH 4
#define M_TOK (BATCH * T_SEQ)   // 8192

// Q pre-scale: 1/sqrt(64) * log2(e)  -> softmax computed in exp2 domain
#define Q_SCALE 0.1803368801111137f
#define DEFER_THR 8.0f

#define AS1 __attribute__((address_space(1)))
#define AS3 __attribute__((address_space(3)))

__device__ __forceinline__ void gld_lds16(const bf16_t* g, bf16_t* l) {
  __builtin_amdgcn_global_load_lds(
      (const AS1 u32*)(uintptr_t)g,
      (AS3 u32*)(u32)(uintptr_t)l, 16, 0, 0);
}

// v_permlane32_swap_b32: swaps a[32+i] <-> b[i].
__device__ __forceinline__ void plswap(u32& a, u32& b) {
  u32x2 r = __builtin_amdgcn_permlane32_swap(a, b, false, false);
  a = r[0]; b = r[1];
}
__device__ __forceinline__ float xmax32(float x) {
  u32 a = __builtin_bit_cast(u32, x), b = a;
  plswap(a, b);
  return fmaxf(__builtin_bit_cast(float, a), __builtin_bit_cast(float, b));
}
__device__ __forceinline__ float xsum32(float x) {
  u32 a = __builtin_bit_cast(u32, x), b = a;
  plswap(a, b);
  return __builtin_bit_cast(float, a) + __builtin_bit_cast(float, b);
}

__device__ __forceinline__ u32 pack_bf16_pair(float v0, float v1) {
  const unsigned short b0 = __builtin_bit_cast(unsigned short, (bf16_t)v0);
  const unsigned short b1 = __builtin_bit_cast(unsigned short, (bf16_t)v1);
  return ((u32)b1 << 16) | (u32)b0;
}

// ---------------------------------------------------------------------------
// prep (merged): blocks [0,8192) convert x f32->bf16; [8192,12288) transpose
// the four weight matrices (w[k][n] f32 -> wt[n][k] bf16).
// ---------------------------------------------------------------------------
__global__ __launch_bounds__(256) void msa_prep(
    const float* __restrict__ x, bf16_t* __restrict__ xb,
    const float* __restrict__ wq, const float* __restrict__ wk,
    const float* __restrict__ wv, const float* __restrict__ wo,
    bf16_t* __restrict__ wt_qkv, bf16_t* __restrict__ wt_o) {
  __shared__ float tile[32][33];
  const int blk = blockIdx.x;
  if (blk < 8192) {
    const int i = blk * 256 + threadIdx.x;
    const float4 v = ((const float4*)x)[i];
    bf16x4 o;
    o[0] = (bf16_t)v.x; o[1] = (bf16_t)v.y; o[2] = (bf16_t)v.z; o[3] = (bf16_t)v.w;
    ((bf16x4*)xb)[i] = o;
  } else {
    const int b2 = blk - 8192;
    const int a = b2 >> 10;
    const int bx = b2 & 31, by = (b2 >> 5) & 31;
    const float* src = (a == 0) ? wq : (a == 1) ? wk : (a == 2) ? wv : wo;
    bf16_t* dst = (a < 3) ? (wt_qkv + (size_t)a * C_DIM * C_DIM) : wt_o;
    const int tx = threadIdx.x & 31, ty = threadIdx.x >> 5;
    const int bi = by * 32, bj = bx * 32;
#pragma unroll
    for (int p = 0; p < 4; p++) {
      int r = p * 8 + ty;
      tile[r][tx] = src[(size_t)(bi + r) * C_DIM + bj + tx];
    }
    __syncthreads();
#pragma unroll
    for (int p = 0; p < 4; p++) {
      int r = p * 8 + ty;
      dst[(size_t)(bj + r) * C_DIM + bi + tx] = (bf16_t)tile[tx][r];
    }
  }
}

// ---------------------------------------------------------------------------
// GEMM core, R15 geometry: 256x128 tile, 512 threads (8 waves, 4m x 2n of
// 64x64 each), BK=32, 3-deep LDS rotation (3 x 24KB = 72KB -> 2 blocks/CU =
// 16 waves/CU, up from 12 at 128^2/48KB).  Counted vmcnt(3) in-loop (3
// gld_lds per thread per tile) with vmcnt(0) on the last two iterations
// (R12-verified tail invariant), XOR-swizzled LDS, setprio on MFMA cluster.
//   buffer: A 16KB [256 rows][4 slots 16B] | B 8KB at +16384.
// ---------------------------------------------------------------------------
#define GQ_BUF 24576

#define GEMM_CORE(APTR, BPTR, NT)                                              \
  __shared__ __align__(16) char lds[3 * GQ_BUF];                               \
  const int tid = threadIdx.x;                                                 \
  const int w = tid >> 6, lane = tid & 63;                                     \
  const int lr = lane & 15, lg = lane >> 4;                                    \
  const int m0 = blockIdx.y * 256;                                             \
  const int n0 = blockIdx.x * 128;                                             \
  const int wm = (w >> 1) * 64, wn = (w & 1) * 64;                             \
  const int rsw = (lg * 16) ^ ((lr & 3) << 4);                                 \
  int Aoff[4], Boff[4];                                                        \
  _Pragma("unroll") for (int f = 0; f < 4; f++) {                              \
    Aoff[f] = (wm + f * 16 + lr) * 64 + rsw;                                   \
    Boff[f] = 16384 + (wn + f * 16 + lr) * 64 + rsw;                           \
  }                                                                            \
  const int srow = tid >> 2;                                                   \
  const int scol = (((tid & 3) ^ (srow & 3))) * 8;                             \
  const bf16_t* gA0 = (APTR) + (size_t)(m0 + srow) * C_DIM + scol;             \
  const bf16_t* gA1 = (APTR) + (size_t)(m0 + 128 + srow) * C_DIM + scol;       \
  const bf16_t* gB0 = (BPTR) + (size_t)(n0 + srow) * C_DIM + scol;             \
  f32x4 acc[4][4];                                                             \
  _Pragma("unroll") for (int i = 0; i < 4; i++)                                \
    _Pragma("unroll") for (int j = 0; j < 4; j++)                              \
      acc[i][j] = (f32x4){0.f, 0.f, 0.f, 0.f};                                 \
  GSTG(0, 0);                                                                  \
  GSTG(1, GQ_BUF);                                                             \
  asm volatile("s_waitcnt vmcnt(3)" ::: "memory");                             \
  __builtin_amdgcn_s_barrier();                                                \
  __builtin_amdgcn_sched_barrier(0);                                           \
  int cb = 0;                                                                  \
  for (int kt = 0; kt < (NT); ++kt) {                                          \
    const char* base = lds + cb * GQ_BUF;                                      \
    bf16x8 a[4], b[4];                                                         \
    _Pragma("unroll") for (int f = 0; f < 4; f++) {                            \
      a[f] = *(const bf16x8*)(base + Aoff[f]);                                 \
      b[f] = *(const bf16x8*)(base + Boff[f]);                                 \
    }                                                                          \
    if (kt < (NT)-2) {                                                         \
      int sb = cb + 2; if (sb >= 3) sb -= 3;                                   \
      GSTG(kt + 2, sb * GQ_BUF);                                               \
    }                                                                          \
    __builtin_amdgcn_s_setprio(1);                                             \
    _Pragma("unroll") for (int mf = 0; mf < 4; mf++)                           \
      _Pragma("unroll") for (int nf = 0; nf < 4; nf++)                         \
        acc[mf][nf] = __builtin_amdgcn_mfma_f32_16x16x32_bf16(                 \
            a[mf], b[nf], acc[mf][nf], 0, 0, 0);                               \
    __builtin_amdgcn_s_setprio(0);                                             \
    if (kt < (NT)-2) {                                                         \
      asm volatile("s_waitcnt vmcnt(3)" ::: "memory");                         \
    } else {                                                                   \
      asm volatile("s_waitcnt vmcnt(0)" ::: "memory");                         \
    }                                                                          \
    __builtin_amdgcn_s_barrier();                                              \
    __builtin_amdgcn_sched_barrier(0);                                         \
    if (++cb == 3) cb = 0;                                                     \
  }

#define GSTG(KT, BB)                                                           \
  {                                                                            \
    bf16_t* d_ = (bf16_t*)(lds + (BB));                                        \
    gld_lds16(gA0 + (KT) * 32, d_ + tid * 8);                                  \
    gld_lds16(gA1 + (KT) * 32, d_ + 4096 + tid * 8);                           \
    gld_lds16(gB0 + (KT) * 32, d_ + 8192 + tid * 8);                           \
  }

// ---------------------------------------------------------------------------
// QKV GEMM -> Q (scaled), K, Vt.  V-blocks use packed 8B scatter.
// ---------------------------------------------------------------------------
__global__ __launch_bounds__(512, 4) void msa_gemm_qkv(
    const bf16_t* __restrict__ xb, const bf16_t* __restrict__ wt,
    const float* __restrict__ bq, const float* __restrict__ bk,
    const float* __restrict__ bv,
    bf16_t* __restrict__ qo, bf16_t* __restrict__ ko, bf16_t* __restrict__ vto) {
  GEMM_CORE(xb, wt, 32)

  const int g = n0 >> 10;  // uniform per block (1024 % 128 == 0)
  if (g == 2) {
#pragma unroll
    for (int nb = 0; nb < 4; nb++) {
      const int c = ((n0 + wn) & 1023) + nb * 16 + lr;
      const int h = c >> 6, d = c & 63;
      const float bias = bv[c];
      bf16_t* vrow = vto + (((size_t)((m0 >> 11) * NH + h)) * DH + d) * T_SEQ;
#pragma unroll
      for (int mb = 0; mb < 4; mb++) {
        const int t = (m0 & 2047) + wm + mb * 16 + lg * 4;
        u32x2 pr;
        pr[0] = pack_bf16_pair(acc[mb][nb][0] + bias, acc[mb][nb][1] + bias);
        pr[1] = pack_bf16_pair(acc[mb][nb][2] + bias, acc[mb][nb][3] + bias);
        *reinterpret_cast<u32x2*>(vrow + t) = pr;
      }
    }
  } else {
#pragma unroll
    for (int nb = 0; nb < 4; nb++) {
      const int n = n0 + wn + nb * 16 + lr;
      const int c = n & 1023, h = c >> 6, d = c & 63;
      const float bias = (g == 0) ? bq[c] : bk[c];
#pragma unroll
      for (int mb = 0; mb < 4; mb++) {
#pragma unroll
        for (int r = 0; r < 4; r++) {
          const int m = m0 + wm + mb * 16 + lg * 4 + r;
          const int bi = m >> 11, t = m & (T_SEQ - 1);
          float v = acc[mb][nb][r] + bias;
          if (g == 0)
            qo[(((size_t)bi * NH + h) * T_SEQ + t) * DH + d] = (bf16_t)(v * Q_SCALE);
          else
            ko[(((size_t)bi * NH + h) * T_SEQ + t) * DH + d] = (bf16_t)v;
        }
      }
    }
  }
}

// ---------------------------------------------------------------------------
// Output projection
// ---------------------------------------------------------------------------
__global__ __launch_bounds__(512, 4) void msa_gemm_out(
    const bf16_t* __restrict__ ab, const bf16_t* __restrict__ wt,
    const float* __restrict__ bo, float* __restrict__ out) {
  GEMM_CORE(ab, wt, 32)

#pragma unroll
  for (int nb = 0; nb < 4; nb++) {
    const int n = n0 + wn + nb * 16 + lr;
    const float bias = bo[n];
#pragma unroll
    for (int mb = 0; mb < 4; mb++) {
#pragma unroll
      for (int r = 0; r < 4; r++) {
        const int m = m0 + wm + mb * 16 + lg * 4 + r;
        out[(size_t)m * C_DIM + n] = acc[mb][nb][r] + bias;
      }
    }
  }
}

// ---------------------------------------------------------------------------
// attn: softmax + pack helpers (permlane, no LDS)
// ---------------------------------------------------------------------------
__device__ __forceinline__ void pack_frag(const f32x16& s, bf16x8& pa0, bf16x8& pa1) {
  u32 pk8[8];
#pragma unroll
  for (int i = 0; i < 8; i++) pk8[i] = pack_bf16_pair(s[2 * i], s[2 * i + 1]);
  u32 f0w0 = pk8[0], f0w2 = pk8[2];
  u32 f0w1 = pk8[1], f0w3 = pk8[3];
  u32 f1w0 = pk8[4], f1w2 = pk8[6];
  u32 f1w1 = pk8[5], f1w3 = pk8[7];
  plswap(f0w0, f0w2);
  plswap(f0w1, f0w3);
  plswap(f1w0, f1w2);
  plswap(f1w1, f1w3);
  const u32x4 q0v = {f0w0, f0w1, f0w2, f0w3};
  const u32x4 q1v = {f1w0, f1w1, f1w2, f1w3};
  pa0 = __builtin_bit_cast(bf16x8, q0v);
  pa1 = __builtin_bit_cast(bf16x8, q1v);
}

__device__ __forceinline__ void sm_pack(f32x16& s, float& m_run, float& l_run,
                                        f32x16& o0, f32x16& o1,
                                        bf16x8& pa0, bf16x8& pa1) {
  float t0 = fmaxf(fmaxf(s[0], s[1]), s[2]);
  float t1 = fmaxf(fmaxf(s[3], s[4]), s[5]);
  float t2 = fmaxf(fmaxf(s[6], s[7]), s[8]);
  float t3 = fmaxf(fmaxf(s[9], s[10]), s[11]);
  float t4 = fmaxf(fmaxf(s[12], s[13]), s[14]);
  float t5 = fmaxf(fmaxf(t0, t1), s[15]);
  float mt = fmaxf(fmaxf(fmaxf(t2, t3), t4), t5);
  mt = xmax32(mt);

  if (__any(mt > m_run + DEFER_THR)) {
    const float mnew = fmaxf(m_run, mt);
    const float al = __builtin_amdgcn_exp2f(m_run - mnew);
    m_run = mnew;
    l_run *= al;
#pragma unroll
    for (int r = 0; r < 16; r++) { o0[r] *= al; o1[r] *= al; }
  }

#pragma unroll
  for (int r = 0; r < 16; r++) s[r] = __builtin_amdgcn_exp2f(s[r] - m_run);
  {
    float a0 = (s[0] + s[1]) + (s[2] + s[3]);
    float a1 = (s[4] + s[5]) + (s[6] + s[7]);
    float a2 = (s[8] + s[9]) + (s[10] + s[11]);
    float a3 = (s[12] + s[13]) + (s[14] + s[15]);
    l_run += xsum32((a0 + a1) + (a2 + a3));
  }
  pack_frag(s, pa0, pa1);
}

__device__ __forceinline__ void store_o(f32x16& o0, f32x16& o1, float l_fin,
                                        bf16_t* __restrict__ orow, const int hi) {
  const float inv = 1.0f / l_fin;
#pragma unroll
  for (int db = 0; db < 2; db++) {
#pragma unroll
    for (int r = 0; r < 16; r += 2) {
      const int d = db * 32 + (r & 3) + 8 * (r >> 2) + 4 * hi;
      const float v0 = (db ? o1[r] : o0[r]) * inv;
      const float v1 = (db ? o1[r + 1] : o0[r + 1]) * inv;
      *reinterpret_cast<u32*>(orow + d) = pack_bf16_pair(v0, v1);
    }
  }
}

// ---------------------------------------------------------------------------
// Flash attention (causal): LDS-staged K/V shared across 4 waves, 3-buffer
// counted-vmcnt rotation (R14).
// ---------------------------------------------------------------------------
__global__ __launch_bounds__(256, 2) void msa_attn_lds(
    const bf16_t* __restrict__ Q, const bf16_t* __restrict__ K,
    const bf16_t* __restrict__ Vt, bf16_t* __restrict__ O) {
  __shared__ __align__(16) char lds[3 * 8192];  // 3 x [K 4KB | V 4KB]
  const int tid = threadIdx.x;
  const int w = tid >> 6;
  const int lane = tid & 63;
  const int l31 = lane & 31;
  const int hi = lane >> 5;
  const int bh = blockIdx.x;
  const int pg = blockIdx.y;          // pg=0 (longest) dispatched first
  const int p = pg * 4 + w;
  const int tS = p, tL = 63 - p;
  const int q0S = tS * 32, q0L = tL * 32;
  const int KT_MAX = 63 - 4 * pg;

  const bf16_t* Qh = Q + (size_t)bh * T_SEQ * DH;
  const bf16_t* Kh = K + (size_t)bh * T_SEQ * DH;
  const bf16_t* Vh = Vt + (size_t)bh * DH * T_SEQ;

  bf16x8 qfL[4], qfS[4];
#pragma unroll
  for (int dc = 0; dc < 4; dc++) {
    qfL[dc] = *(const bf16x8*)(Qh + (size_t)(q0L + l31) * DH + dc * 16 + hi * 8);
    qfS[dc] = *(const bf16x8*)(Qh + (size_t)(q0S + l31) * DH + dc * 16 + hi * 8);
  }

  f32x16 oL0, oL1, oS0, oS1;
#pragma unroll
  for (int r = 0; r < 16; r++) { oL0[r] = 0.f; oL1[r] = 0.f; oS0[r] = 0.f; oS1[r] = 0.f; }
  float mL = -1e30f, lL = 0.f, mS = -1e30f, lS = 0.f;
  const f32x16 z16 = {};

  const int ksw = (l31 & 7) << 4;
  const int vsw = (l31 & 3) << 4;
  const int krow = tid >> 3;
  const int kce = ((16 * (tid & 7)) ^ ((krow & 7) << 4)) >> 1;
  const int vrow = tid >> 2;
  const int vce = ((16 * (tid & 3)) ^ ((vrow & 3) << 4)) >> 1;

#define STAGE(KT, BUF)                                                         \
  {                                                                            \
    const int jj = (KT) * 32;                                                  \
    bf16_t* base_ = (bf16_t*)(lds + (BUF) * 8192);                             \
    gld_lds16(Kh + (size_t)(jj + krow) * DH + kce, base_ + tid * 8);           \
    gld_lds16(Vh + (size_t)vrow * T_SEQ + jj + vce, base_ + 2048 + tid * 8);   \
  }

  STAGE(0, 0);
  STAGE(1, 1);
  asm volatile("s_waitcnt vmcnt(2)" ::: "memory");
  __builtin_amdgcn_s_barrier();
  __builtin_amdgcn_sched_barrier(0);

  int cb = 0;
  for (int kt = 0; kt <= KT_MAX; ++kt) {
    if (kt + 2 <= KT_MAX) {
      int sb = cb + 2; if (sb >= 3) sb -= 3;
      STAGE(kt + 2, sb);
    }

    const bool doL = (kt <= tL);
    if (doL) {
      const char* kb = lds + cb * 8192;
      const char* vb = kb + 4096;
      bf16x8 kf[4];
#pragma unroll
      for (int dc = 0; dc < 4; dc++)
        kf[dc] = *(const bf16x8*)(kb + l31 * 128 + ((dc * 32 + hi * 16) ^ ksw));
      const bf16x8 vf00 = *(const bf16x8*)(vb + l31 * 64 + ((hi * 16) ^ vsw));
      const bf16x8 vf01 = *(const bf16x8*)(vb + l31 * 64 + ((32 + hi * 16) ^ vsw));
      const bf16x8 vf10 = *(const bf16x8*)(vb + (32 + l31) * 64 + ((hi * 16) ^ vsw));
      const bf16x8 vf11 = *(const bf16x8*)(vb + (32 + l31) * 64 + ((32 + hi * 16) ^ vsw));

      const bool doS = (kt <= tS);
      f32x16 sL = __builtin_amdgcn_mfma_f32_32x32x16_bf16(kf[0], qfL[0], z16, 0, 0, 0);
#pragma unroll
      for (int dc = 1; dc < 4; dc++)
        sL = __builtin_amdgcn_mfma_f32_32x32x16_bf16(kf[dc], qfL[dc], sL, 0, 0, 0);
      f32x16 sS;
      if (doS) {
        sS = __builtin_amdgcn_mfma_f32_32x32x16_bf16(kf[0], qfS[0], z16, 0, 0, 0);
#pragma unroll
        for (int dc = 1; dc < 4; dc++)
          sS = __builtin_amdgcn_mfma_f32_32x32x16_bf16(kf[dc], qfS[dc], sS, 0, 0, 0);
      }
      if (kt == tL) {
#pragma unroll
        for (int r = 0; r < 16; r++) {
          const int jrow = (r & 3) + 8 * (r >> 2) + 4 * hi;
          if (jrow > l31) sL[r] = -1e30f;
        }
      }
      if (kt == tS) {
#pragma unroll
        for (int r = 0; r < 16; r++) {
          const int jrow = (r & 3) + 8 * (r >> 2) + 4 * hi;
          if (jrow > l31) sS[r] = -1e30f;
        }
      }
      bf16x8 paL0, paL1;
      sm_pack(sL, mL, lL, oL0, oL1, paL0, paL1);
      oL0 = __builtin_amdgcn_mfma_f32_32x32x16_bf16(vf00, paL0, oL0, 0, 0, 0);
      oL1 = __builtin_amdgcn_mfma_f32_32x32x16_bf16(vf10, paL0, oL1, 0, 0, 0);
      oL0 = __builtin_amdgcn_mfma_f32_32x32x16_bf16(vf01, paL1, oL0, 0, 0, 0);
      oL1 = __builtin_amdgcn_mfma_f32_32x32x16_bf16(vf11, paL1, oL1, 0, 0, 0);
      if (doS) {
        bf16x8 paS0, paS1;
        sm_pack(sS, mS, lS, oS0, oS1, paS0, paS1);
        oS0 = __builtin_amdgcn_mfma_f32_32x32x16_bf16(vf00, paS0, oS0, 0, 0, 0);
        oS1 = __builtin_amdgcn_mfma_f32_32x32x16_bf16(vf10, paS0, oS1, 0, 0, 0);
        oS0 = __builtin_amdgcn_mfma_f32_32x32x16_bf16(vf01, paS1, oS0, 0, 0, 0);
        oS1 = __builtin_amdgcn_mfma_f32_32x32x16_bf16(vf11, paS1, oS1, 0, 0, 0);
      }
    }

    if (kt < KT_MAX - 1) {
      asm volatile("s_waitcnt vmcnt(2)" ::: "memory");
    } else {
      asm volatile("s_waitcnt vmcnt(0)" ::: "memory");
    }
    __builtin_amdgcn_s_barrier();
    __builtin_amdgcn_sched_barrier(0);
    if (++cb == 3) cb = 0;
  }
#undef STAGE

  const int b = bh >> 4, h = bh & 15;
  store_o(oL0, oL1, lL, O + ((size_t)b * T_SEQ + q0L + l31) * C_DIM + h * DH, hi);
  store_o(oS0, oS1, lS, O + ((size_t)b * T_SEQ + q0S + l31) * C_DIM + h * DH, hi);
}

// ---------------------------------------------------------------------------
// launch
// ---------------------------------------------------------------------------
extern "C" void kernel_launch(void* const* d_in, const int* in_sizes, int n_in,
                              void* d_out, int out_size, void* d_ws, size_t ws_size,
                              hipStream_t stream) {
  const float* x  = (const float*)d_in[0];
  const float* wq = (const float*)d_in[2];
  const float* bq = (const float*)d_in[3];
  const float* wk = (const float*)d_in[4];
  const float* bk = (const float*)d_in[5];
  const float* wv = (const float*)d_in[6];
  const float* bv = (const float*)d_in[7];
  const float* wo = (const float*)d_in[8];
  const float* bo = (const float*)d_in[9];

  char* ws = (char*)d_ws;
  bf16_t* xb     = (bf16_t*)(ws);
  bf16_t* wt_qkv = (bf16_t*)(ws + (16ull << 20));
  bf16_t* wt_o   = (bf16_t*)(ws + (22ull << 20));
  bf16_t* qb     = (bf16_t*)(ws + (24ull << 20));
  bf16_t* kb     = (bf16_t*)(ws + (40ull << 20));
  bf16_t* vtb    = (bf16_t*)(ws + (56ull << 20));
  bf16_t* attn_o = xb;  // alias: xb dead after QKV GEMM

  msa_prep<<<12288, 256, 0, stream>>>(x, xb, wq, wk, wv, wo, wt_qkv, wt_o);
  msa_gemm_qkv<<<dim3(24, 32), 512, 0, stream>>>(xb, wt_qkv, bq, bk, bv, qb, kb, vtb);
  msa_attn_lds<<<dim3(64, 8), 256, 0, stream>>>(qb, kb, vtb, attn_o);
  msa_gemm_out<<<dim3(8, 32), 512, 0, stream>>>(attn_o, wt_o, bo, (float*)d_out);
}

// Round 16
// 161.216 us; speedup vs baseline: 1.0527x; 1.0057x over previous
//
#include <hip/hip_runtime.h>

typedef __bf16 bf16_t;
typedef bf16_t bf16x8 __attribute__((ext_vector_type(8)));
typedef bf16_t bf16x4 __attribute__((ext_vector_type(4)));
typedef float  f32x4  __attribute__((ext_vector_type(4)));
typedef float  f32x16 __attribute__((ext_vector_type(16)));
typedef unsigned int u32;
typedef u32 u32x2 __attribute__((ext_vector_type(2)));
typedef u32 u32x4 __attribute__((ext_vector_type(4)));

#define T_SEQ 2048
#define C_DIM 1024
#define NH    16
#define DH    64
#define BATCH 4
#define M_TOK (BATCH * T_SEQ)   // 8192

// Q pre-scale: 1/sqrt(64) * log2(e)  -> softmax computed in exp2 domain
#define Q_SCALE 0.1803368801111137f
#define DEFER_THR 8.0f

#define AS1 __attribute__((address_space(1)))
#define AS3 __attribute__((address_space(3)))

__device__ __forceinline__ void gld_lds16(const bf16_t* g, bf16_t* l) {
  __builtin_amdgcn_global_load_lds(
      (const AS1 u32*)(uintptr_t)g,
      (AS3 u32*)(u32)(uintptr_t)l, 16, 0, 0);
}

// v_permlane32_swap_b32: swaps a[32+i] <-> b[i].
__device__ __forceinline__ void plswap(u32& a, u32& b) {
  u32x2 r = __builtin_amdgcn_permlane32_swap(a, b, false, false);
  a = r[0]; b = r[1];
}
__device__ __forceinline__ float xmax32(float x) {
  u32 a = __builtin_bit_cast(u32, x), b = a;
  plswap(a, b);
  return fmaxf(__builtin_bit_cast(float, a), __builtin_bit_cast(float, b));
}
__device__ __forceinline__ float xsum32(float x) {
  u32 a = __builtin_bit_cast(u32, x), b = a;
  plswap(a, b);
  return __builtin_bit_cast(float, a) + __builtin_bit_cast(float, b);
}

__device__ __forceinline__ u32 pack_bf16_pair(float v0, float v1) {
  const unsigned short b0 = __builtin_bit_cast(unsigned short, (bf16_t)v0);
  const unsigned short b1 = __builtin_bit_cast(unsigned short, (bf16_t)v1);
  return ((u32)b1 << 16) | (u32)b0;
}

// ---------------------------------------------------------------------------
// prep (merged): blocks [0,8192) convert x f32->bf16; [8192,12288) transpose
// the four weight matrices (w[k][n] f32 -> wt[n][k] bf16).
// ---------------------------------------------------------------------------
__global__ __launch_bounds__(256) void msa_prep(
    const float* __restrict__ x, bf16_t* __restrict__ xb,
    const float* __restrict__ wq, const float* __restrict__ wk,
    const float* __restrict__ wv, const float* __restrict__ wo,
    bf16_t* __restrict__ wt_qkv, bf16_t* __restrict__ wt_o) {
  __shared__ float tile[32][33];
  const int blk = blockIdx.x;
  if (blk < 8192) {
    const int i = blk * 256 + threadIdx.x;
    const float4 v = ((const float4*)x)[i];
    bf16x4 o;
    o[0] = (bf16_t)v.x; o[1] = (bf16_t)v.y; o[2] = (bf16_t)v.z; o[3] = (bf16_t)v.w;
    ((bf16x4*)xb)[i] = o;
  } else {
    const int b2 = blk - 8192;
    const int a = b2 >> 10;
    const int bx = b2 & 31, by = (b2 >> 5) & 31;
    const float* src = (a == 0) ? wq : (a == 1) ? wk : (a == 2) ? wv : wo;
    bf16_t* dst = (a < 3) ? (wt_qkv + (size_t)a * C_DIM * C_DIM) : wt_o;
    const int tx = threadIdx.x & 31, ty = threadIdx.x >> 5;
    const int bi = by * 32, bj = bx * 32;
#pragma unroll
    for (int p = 0; p < 4; p++) {
      int r = p * 8 + ty;
      tile[r][tx] = src[(size_t)(bi + r) * C_DIM + bj + tx];
    }
    __syncthreads();
#pragma unroll
    for (int p = 0; p < 4; p++) {
      int r = p * 8 + ty;
      dst[(size_t)(bj + r) * C_DIM + bi + tx] = (bf16_t)tile[tx][r];
    }
  }
}

// ---------------------------------------------------------------------------
// GEMM core (R15-verified): 256x128 tile, 512 threads (8 waves), BK=32,
// 3-deep LDS rotation (72KB -> 2 blocks/CU = 16 waves/CU), counted vmcnt(3)
// in-loop with vmcnt(0) on the last two iterations, XOR-swizzled LDS,
// setprio on the MFMA cluster.
// ---------------------------------------------------------------------------
#define GQ_BUF 24576

#define GEMM_CORE(APTR, BPTR, NT)                                              \
  __shared__ __align__(16) char lds[3 * GQ_BUF];                               \
  const int tid = threadIdx.x;                                                 \
  const int w = tid >> 6, lane = tid & 63;                                     \
  const int lr = lane & 15, lg = lane >> 4;                                    \
  const int m0 = blockIdx.y * 256;                                             \
  const int n0 = blockIdx.x * 128;                                             \
  const int wm = (w >> 1) * 64, wn = (w & 1) * 64;                             \
  const int rsw = (lg * 16) ^ ((lr & 3) << 4);                                 \
  int Aoff[4], Boff[4];                                                        \
  _Pragma("unroll") for (int f = 0; f < 4; f++) {                              \
    Aoff[f] = (wm + f * 16 + lr) * 64 + rsw;                                   \
    Boff[f] = 16384 + (wn + f * 16 + lr) * 64 + rsw;                           \
  }                                                                            \
  const int srow = tid >> 2;                                                   \
  const int scol = (((tid & 3) ^ (srow & 3))) * 8;                             \
  const bf16_t* gA0 = (APTR) + (size_t)(m0 + srow) * C_DIM + scol;             \
  const bf16_t* gA1 = (APTR) + (size_t)(m0 + 128 + srow) * C_DIM + scol;       \
  const bf16_t* gB0 = (BPTR) + (size_t)(n0 + srow) * C_DIM + scol;             \
  f32x4 acc[4][4];                                                             \
  _Pragma("unroll") for (int i = 0; i < 4; i++)                                \
    _Pragma("unroll") for (int j = 0; j < 4; j++)                              \
      acc[i][j] = (f32x4){0.f, 0.f, 0.f, 0.f};                                 \
  GSTG(0, 0);                                                                  \
  GSTG(1, GQ_BUF);                                                             \
  asm volatile("s_waitcnt vmcnt(3)" ::: "memory");                             \
  __builtin_amdgcn_s_barrier();                                                \
  __builtin_amdgcn_sched_barrier(0);                                           \
  int cb = 0;                                                                  \
  for (int kt = 0; kt < (NT); ++kt) {                                          \
    const char* base = lds + cb * GQ_BUF;                                      \
    bf16x8 a[4], b[4];                                                         \
    _Pragma("unroll") for (int f = 0; f < 4; f++) {                            \
      a[f] = *(const bf16x8*)(base + Aoff[f]);                                 \
      b[f] = *(const bf16x8*)(base + Boff[f]);                                 \
    }                                                                          \
    if (kt < (NT)-2) {                                                         \
      int sb = cb + 2; if (sb >= 3) sb -= 3;                                   \
      GSTG(kt + 2, sb * GQ_BUF);                                               \
    }                                                                          \
    __builtin_amdgcn_s_setprio(1);                                             \
    _Pragma("unroll") for (int mf = 0; mf < 4; mf++)                           \
      _Pragma("unroll") for (int nf = 0; nf < 4; nf++)                         \
        acc[mf][nf] = __builtin_amdgcn_mfma_f32_16x16x32_bf16(                 \
            a[mf], b[nf], acc[mf][nf], 0, 0, 0);                               \
    __builtin_amdgcn_s_setprio(0);                                             \
    if (kt < (NT)-2) {                                                         \
      asm volatile("s_waitcnt vmcnt(3)" ::: "memory");                         \
    } else {                                                                   \
      asm volatile("s_waitcnt vmcnt(0)" ::: "memory");                         \
    }                                                                          \
    __builtin_amdgcn_s_barrier();                                              \
    __builtin_amdgcn_sched_barrier(0);                                         \
    if (++cb == 3) cb = 0;                                                     \
  }

#define GSTG(KT, BB)                                                           \
  {                                                                            \
    bf16_t* d_ = (bf16_t*)(lds + (BB));                                        \
    gld_lds16(gA0 + (KT) * 32, d_ + tid * 8);                                  \
    gld_lds16(gA1 + (KT) * 32, d_ + 4096 + tid * 8);                           \
    gld_lds16(gB0 + (KT) * 32, d_ + 8192 + tid * 8);                           \
  }

// ---------------------------------------------------------------------------
// QKV GEMM -> Q (scaled), K, Vt.  V-blocks use packed 8B scatter.
// ---------------------------------------------------------------------------
__global__ __launch_bounds__(512, 4) void msa_gemm_qkv(
    const bf16_t* __restrict__ xb, const bf16_t* __restrict__ wt,
    const float* __restrict__ bq, const float* __restrict__ bk,
    const float* __restrict__ bv,
    bf16_t* __restrict__ qo, bf16_t* __restrict__ ko, bf16_t* __restrict__ vto) {
  GEMM_CORE(xb, wt, 32)

  const int g = n0 >> 10;  // uniform per block (1024 % 128 == 0)
  if (g == 2) {
#pragma unroll
    for (int nb = 0; nb < 4; nb++) {
      const int c = ((n0 + wn) & 1023) + nb * 16 + lr;
      const int h = c >> 6, d = c & 63;
      const float bias = bv[c];
      bf16_t* vrow = vto + (((size_t)((m0 >> 11) * NH + h)) * DH + d) * T_SEQ;
#pragma unroll
      for (int mb = 0; mb < 4; mb++) {
        const int t = (m0 & 2047) + wm + mb * 16 + lg * 4;
        u32x2 pr;
        pr[0] = pack_bf16_pair(acc[mb][nb][0] + bias, acc[mb][nb][1] + bias);
        pr[1] = pack_bf16_pair(acc[mb][nb][2] + bias, acc[mb][nb][3] + bias);
        *reinterpret_cast<u32x2*>(vrow + t) = pr;
      }
    }
  } else {
#pragma unroll
    for (int nb = 0; nb < 4; nb++) {
      const int n = n0 + wn + nb * 16 + lr;
      const int c = n & 1023, h = c >> 6, d = c & 63;
      const float bias = (g == 0) ? bq[c] : bk[c];
#pragma unroll
      for (int mb = 0; mb < 4; mb++) {
#pragma unroll
        for (int r = 0; r < 4; r++) {
          const int m = m0 + wm + mb * 16 + lg * 4 + r;
          const int bi = m >> 11, t = m & (T_SEQ - 1);
          float v = acc[mb][nb][r] + bias;
          if (g == 0)
            qo[(((size_t)bi * NH + h) * T_SEQ + t) * DH + d] = (bf16_t)(v * Q_SCALE);
          else
            ko[(((size_t)bi * NH + h) * T_SEQ + t) * DH + d] = (bf16_t)v;
        }
      }
    }
  }
}

// ---------------------------------------------------------------------------
// Output projection
// ---------------------------------------------------------------------------
__global__ __launch_bounds__(512, 4) void msa_gemm_out(
    const bf16_t* __restrict__ ab, const bf16_t* __restrict__ wt,
    const float* __restrict__ bo, float* __restrict__ out) {
  GEMM_CORE(ab, wt, 32)

#pragma unroll
  for (int nb = 0; nb < 4; nb++) {
    const int n = n0 + wn + nb * 16 + lr;
    const float bias = bo[n];
#pragma unroll
    for (int mb = 0; mb < 4; mb++) {
#pragma unroll
      for (int r = 0; r < 4; r++) {
        const int m = m0 + wm + mb * 16 + lg * 4 + r;
        out[(size_t)m * C_DIM + n] = acc[mb][nb][r] + bias;
      }
    }
  }
}

// ---------------------------------------------------------------------------
// attn: softmax + pack helpers (permlane, no LDS)
// ---------------------------------------------------------------------------
__device__ __forceinline__ void pack_frag(const f32x16& s, bf16x8& pa0, bf16x8& pa1) {
  u32 pk8[8];
#pragma unroll
  for (int i = 0; i < 8; i++) pk8[i] = pack_bf16_pair(s[2 * i], s[2 * i + 1]);
  u32 f0w0 = pk8[0], f0w2 = pk8[2];
  u32 f0w1 = pk8[1], f0w3 = pk8[3];
  u32 f1w0 = pk8[4], f1w2 = pk8[6];
  u32 f1w1 = pk8[5], f1w3 = pk8[7];
  plswap(f0w0, f0w2);
  plswap(f0w1, f0w3);
  plswap(f1w0, f1w2);
  plswap(f1w1, f1w3);
  const u32x4 q0v = {f0w0, f0w1, f0w2, f0w3};
  const u32x4 q1v = {f1w0, f1w1, f1w2, f1w3};
  pa0 = __builtin_bit_cast(bf16x8, q0v);
  pa1 = __builtin_bit_cast(bf16x8, q1v);
}

__device__ __forceinline__ void sm_pack(f32x16& s, float& m_run, float& l_run,
                                        f32x16& o0, f32x16& o1,
                                        bf16x8& pa0, bf16x8& pa1) {
  float t0 = fmaxf(fmaxf(s[0], s[1]), s[2]);
  float t1 = fmaxf(fmaxf(s[3], s[4]), s[5]);
  float t2 = fmaxf(fmaxf(s[6], s[7]), s[8]);
  float t3 = fmaxf(fmaxf(s[9], s[10]), s[11]);
  float t4 = fmaxf(fmaxf(s[12], s[13]), s[14]);
  float t5 = fmaxf(fmaxf(t0, t1), s[15]);
  float mt = fmaxf(fmaxf(fmaxf(t2, t3), t4), t5);
  mt = xmax32(mt);

  if (__any(mt > m_run + DEFER_THR)) {
    const float mnew = fmaxf(m_run, mt);
    const float al = __builtin_amdgcn_exp2f(m_run - mnew);
    m_run = mnew;
    l_run *= al;
#pragma unroll
    for (int r = 0; r < 16; r++) { o0[r] *= al; o1[r] *= al; }
  }

#pragma unroll
  for (int r = 0; r < 16; r++) s[r] = __builtin_amdgcn_exp2f(s[r] - m_run);
  {
    float a0 = (s[0] + s[1]) + (s[2] + s[3]);
    float a1 = (s[4] + s[5]) + (s[6] + s[7]);
    float a2 = (s[8] + s[9]) + (s[10] + s[11]);
    float a3 = (s[12] + s[13]) + (s[14] + s[15]);
    l_run += xsum32((a0 + a1) + (a2 + a3));
  }
  pack_frag(s, pa0, pa1);
}

__device__ __forceinline__ void store_o(f32x16& o0, f32x16& o1, float l_fin,
                                        bf16_t* __restrict__ orow, const int hi) {
  const float inv = 1.0f / l_fin;
#pragma unroll
  for (int db = 0; db < 2; db++) {
#pragma unroll
    for (int r = 0; r < 16; r += 2) {
      const int d = db * 32 + (r & 3) + 8 * (r >> 2) + 4 * hi;
      const float v0 = (db ? o1[r] : o0[r]) * inv;
      const float v1 = (db ? o1[r + 1] : o0[r + 1]) * inv;
      *reinterpret_cast<u32*>(orow + d) = pack_bf16_pair(v0, v1);
    }
  }
}

// ---------------------------------------------------------------------------
// Flash attention (causal): LDS-staged K/V shared across 4 waves.
// R16: REVERTED to the R10 2-buffer __syncthreads schedule. The R14 counted
// vmcnt rotation let gld_lds DMA writes run concurrently with ds_reads ->
// 6.36M LDS write/read bank-conflict cycles (R10 measured 0) and attn drifted
// 60 -> 70us. The barrier serializes write-complete before read-start.
// ---------------------------------------------------------------------------
__global__ __launch_bounds__(256, 2) void msa_attn_lds(
    const bf16_t* __restrict__ Q, const bf16_t* __restrict__ K,
    const bf16_t* __restrict__ Vt, bf16_t* __restrict__ O) {
  __shared__ __align__(16) char lds[16384];  // [buf][K 4KB | V 4KB]
  const int tid = threadIdx.x;
  const int w = tid >> 6;
  const int lane = tid & 63;
  const int l31 = lane & 31;
  const int hi = lane >> 5;
  const int bh = blockIdx.x;
  const int pg = blockIdx.y;          // pg=0 (longest) dispatched first
  const int p = pg * 4 + w;
  const int tS = p, tL = 63 - p;
  const int q0S = tS * 32, q0L = tL * 32;
  const int KT_MAX = 63 - 4 * pg;

  const bf16_t* Qh = Q + (size_t)bh * T_SEQ * DH;
  const bf16_t* Kh = K + (size_t)bh * T_SEQ * DH;
  const bf16_t* Vh = Vt + (size_t)bh * DH * T_SEQ;

  bf16x8 qfL[4], qfS[4];
#pragma unroll
  for (int dc = 0; dc < 4; dc++) {
    qfL[dc] = *(const bf16x8*)(Qh + (size_t)(q0L + l31) * DH + dc * 16 + hi * 8);
    qfS[dc] = *(const bf16x8*)(Qh + (size_t)(q0S + l31) * DH + dc * 16 + hi * 8);
  }

  f32x16 oL0, oL1, oS0, oS1;
#pragma unroll
  for (int r = 0; r < 16; r++) { oL0[r] = 0.f; oL1[r] = 0.f; oS0[r] = 0.f; oS1[r] = 0.f; }
  float mL = -1e30f, lL = 0.f, mS = -1e30f, lS = 0.f;
  const f32x16 z16 = {};

  const int ksw = (l31 & 7) << 4;
  const int vsw = (l31 & 3) << 4;
  const int krow = tid >> 3;
  const int kce = ((16 * (tid & 7)) ^ ((krow & 7) << 4)) >> 1;
  const int vrow = tid >> 2;
  const int vce = ((16 * (tid & 3)) ^ ((vrow & 3) << 4)) >> 1;

#define STAGE(KT, BUF)                                                         \
  {                                                                            \
    const int jj = (KT) * 32;                                                  \
    bf16_t* base_ = (bf16_t*)(lds + (BUF) * 8192);                             \
    gld_lds16(Kh + (size_t)(jj + krow) * DH + kce, base_ + tid * 8);           \
    gld_lds16(Vh + (size_t)vrow * T_SEQ + jj + vce, base_ + 2048 + tid * 8);   \
  }

  STAGE(0, 0);
  __syncthreads();

  for (int kt = 0; kt <= KT_MAX; ++kt) {
    const int buf = kt & 1;
    if (kt < KT_MAX) STAGE(kt + 1, buf ^ 1);

    const bool doL = (kt <= tL);
    if (doL) {
      const char* kb = lds + buf * 8192;
      const char* vb = kb + 4096;
      bf16x8 kf[4];
#pragma unroll
      for (int dc = 0; dc < 4; dc++)
        kf[dc] = *(const bf16x8*)(kb + l31 * 128 + ((dc * 32 + hi * 16) ^ ksw));
      const bf16x8 vf00 = *(const bf16x8*)(vb + l31 * 64 + ((hi * 16) ^ vsw));
      const bf16x8 vf01 = *(const bf16x8*)(vb + l31 * 64 + ((32 + hi * 16) ^ vsw));
      const bf16x8 vf10 = *(const bf16x8*)(vb + (32 + l31) * 64 + ((hi * 16) ^ vsw));
      const bf16x8 vf11 = *(const bf16x8*)(vb + (32 + l31) * 64 + ((32 + hi * 16) ^ vsw));

      const bool doS = (kt <= tS);
      f32x16 sL = __builtin_amdgcn_mfma_f32_32x32x16_bf16(kf[0], qfL[0], z16, 0, 0, 0);
#pragma unroll
      for (int dc = 1; dc < 4; dc++)
        sL = __builtin_amdgcn_mfma_f32_32x32x16_bf16(kf[dc], qfL[dc], sL, 0, 0, 0);
      f32x16 sS;
      if (doS) {
        sS = __builtin_amdgcn_mfma_f32_32x32x16_bf16(kf[0], qfS[0], z16, 0, 0, 0);
#pragma unroll
        for (int dc = 1; dc < 4; dc++)
          sS = __builtin_amdgcn_mfma_f32_32x32x16_bf16(kf[dc], qfS[dc], sS, 0, 0, 0);
      }
      if (kt == tL) {
#pragma unroll
        for (int r = 0; r < 16; r++) {
          const int jrow = (r & 3) + 8 * (r >> 2) + 4 * hi;
          if (jrow > l31) sL[r] = -1e30f;
        }
      }
      if (kt == tS) {
#pragma unroll
        for (int r = 0; r < 16; r++) {
          const int jrow = (r & 3) + 8 * (r >> 2) + 4 * hi;
          if (jrow > l31) sS[r] = -1e30f;
        }
      }
      bf16x8 paL0, paL1;
      sm_pack(sL, mL, lL, oL0, oL1, paL0, paL1);
      oL0 = __builtin_amdgcn_mfma_f32_32x32x16_bf16(vf00, paL0, oL0, 0, 0, 0);
      oL1 = __builtin_amdgcn_mfma_f32_32x32x16_bf16(vf10, paL0, oL1, 0, 0, 0);
      oL0 = __builtin_amdgcn_mfma_f32_32x32x16_bf16(vf01, paL1, oL0, 0, 0, 0);
      oL1 = __builtin_amdgcn_mfma_f32_32x32x16_bf16(vf11, paL1, oL1, 0, 0, 0);
      if (doS) {
        bf16x8 paS0, paS1;
        sm_pack(sS, mS, lS, oS0, oS1, paS0, paS1);
        oS0 = __builtin_amdgcn_mfma_f32_32x32x16_bf16(vf00, paS0, oS0, 0, 0, 0);
        oS1 = __builtin_amdgcn_mfma_f32_32x32x16_bf16(vf10, paS0, oS1, 0, 0, 0);
        oS0 = __builtin_amdgcn_mfma_f32_32x32x16_bf16(vf01, paS1, oS0, 0, 0, 0);
        oS1 = __builtin_amdgcn_mfma_f32_32x32x16_bf16(vf11, paS1, oS1, 0, 0, 0);
      }
    }
    __syncthreads();
  }
#undef STAGE

  const int b = bh >> 4, h = bh & 15;
  store_o(oL0, oL1, lL, O + ((size_t)b * T_SEQ + q0L + l31) * C_DIM + h * DH, hi);
  store_o(oS0, oS1, lS, O + ((size_t)b * T_SEQ + q0S + l31) * C_DIM + h * DH, hi);
}

// ---------------------------------------------------------------------------
// launch
// ---------------------------------------------------------------------------
extern "C" void kernel_launch(void* const* d_in, const int* in_sizes, int n_in,
                              void* d_out, int out_size, void* d_ws, size_t ws_size,
                              hipStream_t stream) {
  const float* x  = (const float*)d_in[0];
  const float* wq = (const float*)d_in[2];
  const float* bq = (const float*)d_in[3];
  const float* wk = (const float*)d_in[4];
  const float* bk = (const float*)d_in[5];
  const float* wv = (const float*)d_in[6];
  const float* bv = (const float*)d_in[7];
  const float* wo = (const float*)d_in[8];
  const float* bo = (const float*)d_in[9];

  char* ws = (char*)d_ws;
  bf16_t* xb     = (bf16_t*)(ws);
  bf16_t* wt_qkv = (bf16_t*)(ws + (16ull << 20));
  bf16_t* wt_o   = (bf16_t*)(ws + (22ull << 20));
  bf16_t* qb     = (bf16_t*)(ws + (24ull << 20));
  bf16_t* kb     = (bf16_t*)(ws + (40ull << 20));
  bf16_t* vtb    = (bf16_t*)(ws + (56ull << 20));
  bf16_t* attn_o = xb;  // alias: xb dead after QKV GEMM

  msa_prep<<<12288, 256, 0, stream>>>(x, xb, wq, wk, wv, wo, wt_qkv, wt_o);
  msa_gemm_qkv<<<dim3(24, 32), 512, 0, stream>>>(xb, wt_qkv, bq, bk, bv, qb, kb, vtb);
  msa_attn_lds<<<dim3(64, 8), 256, 0, stream>>>(qb, kb, vtb, attn_o);
  msa_gemm_out<<<dim3(8, 32), 512, 0, stream>>>(attn_o, wt_o, bo, (float*)d_out);
}